// Round 10
// baseline (709.529 us; speedup 1.0000x reference)
//
#include <hip/hip_runtime.h>
#include <math.h>

#define BB 8
#define FF 256
#define SS 1024
#define KK 16
#define ITERS 5

typedef unsigned long long ull;

// ---------- wm stage 1: partial column sums of w ----------
#define ICH 8
__global__ void wm_part_kernel(const float* __restrict__ w, float* __restrict__ part) {
    int j = blockIdx.x * 256 + threadIdx.x;
    int ic = blockIdx.y, b = blockIdx.z;
    const float* wp = w + (size_t)b * SS * SS + (size_t)ic * (SS / ICH) * SS + j;
    float s = 0.f;
#pragma unroll 8
    for (int i = 0; i < SS / ICH; ++i) s += wp[(size_t)i * SS];
    part[((size_t)ic * BB + b) * SS + j] = s;
}

// ---------- d[b][i][j] = sum_f |x[b][f][i] - x[b][f][j]| ----------
// 32x32 wave-private tiles, 2 independent waves per block, 8 KB/block,
// FCD=8 double-buffered global->LDS staging (vmcnt(2)). This round: the
// whole chunk's 16 float4s are prefetched into registers before the MAC
// loop so the ds_read_b128s pipeline (one cold latency per chunk, not 8).
// __launch_bounds__(128,4): 128-VGPR cap, ~100 used -> no spill (R8 lesson:
// (128,8)'s 64-cap spilled acc, WRITE_SIZE 241 MB).
// f ascending (bitwise-matches all passing versions).
#define FCD 8
__device__ __forceinline__ void async_copy16(const float* g, const float* s) {
    __builtin_amdgcn_global_load_lds((const __attribute__((address_space(1))) void*)g,
                                     (__attribute__((address_space(3))) void*)s, 16, 0, 0);
}

__global__ __launch_bounds__(128, 4) void dist_kernel(const float* __restrict__ x,
                                                      float* __restrict__ d) {
    __shared__ float smem[2048];   // per wave (1024): A0 256|B0 256|A1 256|B1 256
    int tid = threadIdx.x;
    int wave = tid >> 6, lane = tid & 63;
    int b = blockIdx.y;
    int w = blockIdx.x * 2 + wave;      // 0..527 triangular tile id (32x32 tiles)
    int it = 0, rem = w;
    while (rem >= 32 - it) { rem -= 32 - it; ++it; }
    int jt = it + rem;
    int i0 = it * 32, j0 = jt * 32;
    const float* xb = x + (size_t)b * FF * SS;
    float* db = d + (size_t)b * SS * SS;
    float* wbase = smem + wave * 1024;
    int ly = lane >> 3, lx = lane & 7;           // 8x8 lane grid, 4x4 each
    int sFl = lane >> 3, sTk = (lane & 7) * 4;   // staging: 8 f-rows x 32 tok/inst

    float acc[4][4] = {};

    auto stage = [&](int c, int h) {
        float* A = wbase + h * 512;
        const float* base = xb + (size_t)c * FCD * SS + (size_t)sFl * SS;
        async_copy16(base + i0 + sTk, A);          // A chunk: 8f x 32tok = 1 inst
        async_copy16(base + j0 + sTk, A + 256);    // B chunk
    };
    auto compute = [&](int h) {
        const float* A = wbase + h * 512;
        const float* B = A + 256;
        float4 a8[FCD], b8[FCD];
#pragma unroll
        for (int f = 0; f < FCD; ++f) {
            a8[f] = *(const float4*)(A + f * 32 + ly * 4);
            b8[f] = *(const float4*)(B + f * 32 + lx * 4);
        }
#pragma unroll
        for (int f = 0; f < FCD; ++f) {
            float av[4] = {a8[f].x, a8[f].y, a8[f].z, a8[f].w};
            float bv[4] = {b8[f].x, b8[f].y, b8[f].z, b8[f].w};
#pragma unroll
            for (int r = 0; r < 4; ++r)
#pragma unroll
                for (int c = 0; c < 4; ++c)
                    acc[r][c] += fabsf(av[r] - bv[c]);
        }
    };

    stage(0, 0);
#pragma unroll 1
    for (int k = 0; k < FF / FCD - 1; ++k) {
        // WAR: ds_reads of the buffer we are about to overwrite have retired
        asm volatile("s_waitcnt lgkmcnt(0)" ::: "memory");
        stage(k + 1, (k + 1) & 1);
        // wait only for chunk k's 2 loads; chunk k+1's 2 stay in flight
        asm volatile("s_waitcnt vmcnt(2)" ::: "memory");
        compute(k & 1);
    }
    asm volatile("s_waitcnt vmcnt(0)" ::: "memory");
    compute(1);   // chunk 31 -> buffer 1

    // direct tile: rows i0+ly*4+r, cols j0+lx*4
#pragma unroll
    for (int r = 0; r < 4; ++r) {
        float4 v = make_float4(acc[r][0], acc[r][1], acc[r][2], acc[r][3]);
        *(float4*)&db[(size_t)(i0 + ly * 4 + r) * SS + j0 + lx * 4] = v;
    }
    if (it != jt) {
        // mirror straight from registers (d bitwise symmetric)
#pragma unroll
        for (int c = 0; c < 4; ++c) {
            float4 v = make_float4(acc[0][c], acc[1][c], acc[2][c], acc[3][c]);
            *(float4*)&db[(size_t)(j0 + lx * 4 + c) * SS + i0 + ly * 4] = v;
        }
    }
}

// ---------- wm finalize + topk (jax.lax.top_k) + initial assign + cnt init ----------
// wm > 0 strictly (means of uniform[0,1)), so float bits are order-monotonic.
__global__ __launch_bounds__(1024) void topk_assign_kernel(const float* __restrict__ part,
                                                           float* __restrict__ wm,
                                                           const float* __restrict__ d,
                                                           int* __restrict__ assign,
                                                           int* __restrict__ cnt) {
    int b = blockIdx.x;
    int tid = threadIdx.x;          // == token index
    int lane = tid & 63, wv = tid >> 6;
    if (tid < ITERS) cnt[tid * BB + b] = 0;   // re-init counters (ws poisoned per call)
    __shared__ ull red[16];
    __shared__ int ctr_s[KK];
    // finalize wm for this batch (same ascending-ic order as before)
    float v = 0.f;
#pragma unroll
    for (int ic = 0; ic < ICH; ++ic) v += part[((size_t)ic * BB + b) * SS + tid];
    v *= (1.0f / SS);
    wm[b * SS + tid] = v;
    // key: value-desc, tie -> smaller index (complemented idx, max-reduce)
    ull key = (((ull)__float_as_uint(v)) << 32) | (ull)(0xFFFFFFFFu - (unsigned)tid);
    for (int k = 0; k < KK; ++k) {
        ull kk = key;
#pragma unroll
        for (int off = 32; off; off >>= 1) {
            ull o = __shfl_down(kk, off, 64);
            if (o > kk) kk = o;
        }
        if (lane == 0) red[wv] = kk;
        __syncthreads();
        if (wv == 0) {
            ull k2 = (lane < 16) ? red[lane] : 0ull;
#pragma unroll
            for (int off = 8; off; off >>= 1) {
                ull o = __shfl_down(k2, off, 64);
                if (o > k2) k2 = o;
            }
            if (lane == 0) red[0] = k2;
        }
        __syncthreads();
        ull W = red[0];
        int widx = (int)(0xFFFFFFFFu - (unsigned)(W & 0xFFFFFFFFu));
        if (tid == widx) key = 0;            // remove winner
        if (tid == 0) ctr_s[k] = widx;
        __syncthreads();                      // protect red[] before next round
    }
    // initial assign: argmin_k d[ctr[k]][i] (d symmetric; coalesced over i)
    const float* db = d + (size_t)b * SS * SS;
    float bv = INFINITY;
    int bk = 0;
#pragma unroll
    for (int k = 0; k < KK; ++k) {
        float vv = db[(size_t)ctr_s[k] * SS + tid];
        if (vv < bv) { bv = vv; bk = k; }    // strict < keeps first k
    }
    assign[b * SS + tid] = bk;
}

// ---------- cost + last-block medoid update + assign/gather, fused ----------
// cost[b][i] = sum_{j: assign[j]==assign[i]} d[i][j]*wm[j], deposited via a
// device-scope ATOMIC store (straight to the coherence point — NO per-block
// cache fences, the R7 killer), drained with vmcnt(0), then a relaxed
// counter fetch_add. The last block per batch re-reads costs via atomic
// loads (bypass stale L1/L2), computes per-cluster argmin (packed-u64 min:
// unique total order == sequential first-index scan), then writes the next
// assign (or, on the last iteration, the final gather).
__global__ __launch_bounds__(256) void costupd_kernel(const float* __restrict__ d,
                                                      const float* __restrict__ wm,
                                                      int* __restrict__ assign,
                                                      float* __restrict__ cost,
                                                      int* __restrict__ cnt,
                                                      const float* __restrict__ x,
                                                      float* __restrict__ out,
                                                      int itr) {
    int b = blockIdx.y;
    int i = blockIdx.x;
    int tid = threadIdx.x;
    int my = assign[b * SS + i];
    const float* drow = d + (size_t)b * SS * SS + (size_t)i * SS;
    float4 dv = *(const float4*)&drow[tid * 4];
    float4 wv4 = *(const float4*)&wm[b * SS + tid * 4];
    int4 av = *(const int4*)&assign[b * SS + tid * 4];
    float s = 0.f;
    s += (av.x == my) ? dv.x * wv4.x : 0.f;
    s += (av.y == my) ? dv.y * wv4.y : 0.f;
    s += (av.z == my) ? dv.z * wv4.z : 0.f;
    s += (av.w == my) ? dv.w * wv4.w : 0.f;
#pragma unroll
    for (int off = 32; off > 0; off >>= 1) s += __shfl_down(s, off, 64);
    __shared__ float ws_s[4];
    __shared__ int is_last;
    if ((tid & 63) == 0) ws_s[tid >> 6] = s;
    __syncthreads();
    if (tid == 0) {
        float c = (ws_s[0] + ws_s[1]) + (ws_s[2] + ws_s[3]);
        __hip_atomic_store(&cost[b * SS + i], c, __ATOMIC_RELAXED,
                           __HIP_MEMORY_SCOPE_AGENT);
        asm volatile("s_waitcnt vmcnt(0)" ::: "memory");  // store globally performed
        int old = __hip_atomic_fetch_add(&cnt[itr * BB + b], 1, __ATOMIC_RELAXED,
                                         __HIP_MEMORY_SCOPE_AGENT);
        is_last = (old == SS - 1);
    }
    __syncthreads();
    if (!is_last) return;

    // ---- updater: runs after all 1024 cost blocks of batch b completed ----
    __shared__ float cost_s[SS];
    __shared__ int assign_s[SS];
    __shared__ int ctr_s[KK];
#pragma unroll
    for (int t = 0; t < 4; ++t) {
        int j = t * 256 + tid;
        cost_s[j] = __hip_atomic_load(&cost[b * SS + j], __ATOMIC_RELAXED,
                                      __HIP_MEMORY_SCOPE_AGENT);
    }
    *(int4*)&assign_s[tid * 4] = *(const int4*)&assign[b * SS + tid * 4];
    __syncthreads();
    int lane = tid & 63, wv = tid >> 6;
    // cost >= 0 finite, so float bits are order-monotonic
#pragma unroll
    for (int kk = 0; kk < 4; ++kk) {
        int k = wv * 4 + kk;                    // 4 waves x 4 clusters
        ull best = ~0ull;
        for (int c = 0; c < SS / 64; ++c) {
            int j = c * 64 + lane;
            if (assign_s[j] == k) {
                ull key = (((ull)__float_as_uint(cost_s[j])) << 32) | (unsigned)j;
                if (key < best) best = key;
            }
        }
#pragma unroll
        for (int off = 32; off; off >>= 1) {
            ull o = __shfl_down(best, off, 64);
            if (o < best) best = o;
        }
        if (lane == 0) ctr_s[k] = (best == ~0ull) ? 0 : (int)(best & 0xFFFFFFFFu);
    }
    __syncthreads();
    const float* db = d + (size_t)b * SS * SS;
    if (itr < ITERS - 1) {
        // next assign: packed-key min => smallest dist, tie smallest k
#pragma unroll
        for (int t = 0; t < 4; ++t) {
            int tok = t * 256 + tid;            // coalesced across tid
            ull bk = ~0ull;
#pragma unroll
            for (int k = 0; k < KK; ++k) {
                float vv = db[(size_t)ctr_s[k] * SS + tok];
                ull key = (((ull)__float_as_uint(vv)) << 32) | (unsigned)k;
                if (key < bk) bk = key;
            }
            assign[b * SS + tok] = (int)(bk & 0xFFFFFFFFu);
        }
    } else {
        // final gather: out[b][f][k] = x[b][f][ctr[k]]
        for (int e = tid; e < FF * KK; e += 256) {
            int f = e >> 4, k = e & 15;
            out[((size_t)b * FF + f) * KK + k] = x[((size_t)b * FF + f) * SS + ctr_s[k]];
        }
    }
}

extern "C" void kernel_launch(void* const* d_in, const int* in_sizes, int n_in,
                              void* d_out, int out_size, void* d_ws, size_t ws_size,
                              hipStream_t stream) {
    const float* x = (const float*)d_in[0];   // [B,F,S]
    const float* w = (const float*)d_in[1];   // [B,S,S]
    float* out = (float*)d_out;               // [B,F,K]

    char* ws = (char*)d_ws;
    float* d = (float*)ws;                              // B*S*S floats = 33.55 MB
    size_t off = (size_t)BB * SS * SS * sizeof(float);
    float* wm = (float*)(ws + off);   off += (size_t)BB * SS * sizeof(float);
    int* assign = (int*)(ws + off);   off += (size_t)BB * SS * sizeof(int);
    float* cost = (float*)(ws + off); off += (size_t)BB * SS * sizeof(float);
    int* cnt = (int*)(ws + off);      off += (size_t)(ITERS * BB + 8) * sizeof(int);
    float* part = (float*)(ws + off); // [ICH][B][S] = 256 KB (non-aliasing:
                                      // consumed by topk AFTER dist runs)

    wm_part_kernel<<<dim3(SS / 256, ICH, BB), 256, 0, stream>>>(w, part);
    // 528 triangular 32x32 wave-tiles per batch, 2 waves (2 tiles) per block
    dist_kernel<<<dim3(264, BB), 128, 0, stream>>>(x, d);
    topk_assign_kernel<<<BB, 1024, 0, stream>>>(part, wm, d, assign, cnt);
    for (int itr = 0; itr < ITERS; ++itr)
        costupd_kernel<<<dim3(SS, BB), 256, 0, stream>>>(d, wm, assign, cost, cnt,
                                                         x, out, itr);
}

// Round 11
// 232.145 us; speedup vs baseline: 3.0564x; 3.0564x over previous
//
#include <hip/hip_runtime.h>
#include <math.h>

#define BB 8
#define FF 256
#define SS 1024
#define KK 16
#define ITERS 5

typedef unsigned long long ull;

// ---------- wm stage 1: partial column sums of w ----------
#define ICH 8
__global__ void wm_part_kernel(const float* __restrict__ w, float* __restrict__ part) {
    int j = blockIdx.x * 256 + threadIdx.x;
    int ic = blockIdx.y, b = blockIdx.z;
    const float* wp = w + (size_t)b * SS * SS + (size_t)ic * (SS / ICH) * SS + j;
    float s = 0.f;
#pragma unroll 16
    for (int i = 0; i < SS / ICH; ++i) s += wp[(size_t)i * SS];
    part[((size_t)ic * BB + b) * SS + j] = s;
}

// ---------- d[b][i][j] = sum_f |x[b][f][i] - x[b][f][j]| ----------
// 32x32 wave-private tiles, 2 independent waves per block, 8 KB/block,
// FCD=8 double-buffered global->LDS staging (vmcnt(2)).
// __launch_bounds__(128,4): 128-VGPR cap, 48 used -> no spill (R8 lesson:
// (128,8)'s 64-cap spilled acc, WRITE_SIZE 241 MB).
// f ascending (bitwise-matches all passing versions).  [R9-measured: 95 us]
#define FCD 8
__device__ __forceinline__ void async_copy16(const float* g, const float* s) {
    __builtin_amdgcn_global_load_lds((const __attribute__((address_space(1))) void*)g,
                                     (__attribute__((address_space(3))) void*)s, 16, 0, 0);
}

__global__ __launch_bounds__(128, 4) void dist_kernel(const float* __restrict__ x,
                                                      float* __restrict__ d) {
    __shared__ float smem[2048];   // per wave (1024): A0 256|B0 256|A1 256|B1 256
    int tid = threadIdx.x;
    int wave = tid >> 6, lane = tid & 63;
    int b = blockIdx.y;
    int w = blockIdx.x * 2 + wave;      // 0..527 triangular tile id (32x32 tiles)
    int it = 0, rem = w;
    while (rem >= 32 - it) { rem -= 32 - it; ++it; }
    int jt = it + rem;
    int i0 = it * 32, j0 = jt * 32;
    const float* xb = x + (size_t)b * FF * SS;
    float* db = d + (size_t)b * SS * SS;
    float* wbase = smem + wave * 1024;
    int ly = lane >> 3, lx = lane & 7;           // 8x8 lane grid, 4x4 each
    int sFl = lane >> 3, sTk = (lane & 7) * 4;   // staging: 8 f-rows x 32 tok/inst

    float acc[4][4] = {};

    auto stage = [&](int c, int h) {
        float* A = wbase + h * 512;
        const float* base = xb + (size_t)c * FCD * SS + (size_t)sFl * SS;
        async_copy16(base + i0 + sTk, A);          // A chunk: 8f x 32tok = 1 inst
        async_copy16(base + j0 + sTk, A + 256);    // B chunk
    };
    auto compute = [&](int h) {
        const float* A = wbase + h * 512;
        const float* B = A + 256;
#pragma unroll
        for (int f = 0; f < FCD; ++f) {
            float4 a = *(const float4*)(A + f * 32 + ly * 4);
            float4 bb = *(const float4*)(B + f * 32 + lx * 4);
            float av[4] = {a.x, a.y, a.z, a.w};
            float bv[4] = {bb.x, bb.y, bb.z, bb.w};
#pragma unroll
            for (int r = 0; r < 4; ++r)
#pragma unroll
                for (int c = 0; c < 4; ++c)
                    acc[r][c] += fabsf(av[r] - bv[c]);
        }
    };

    stage(0, 0);
#pragma unroll 1
    for (int k = 0; k < FF / FCD - 1; ++k) {
        // WAR: ds_reads of the buffer we are about to overwrite have retired
        asm volatile("s_waitcnt lgkmcnt(0)" ::: "memory");
        stage(k + 1, (k + 1) & 1);
        // wait only for chunk k's 2 loads; chunk k+1's 2 stay in flight
        asm volatile("s_waitcnt vmcnt(2)" ::: "memory");
        compute(k & 1);
    }
    asm volatile("s_waitcnt vmcnt(0)" ::: "memory");
    compute(1);   // chunk 31 -> buffer 1

    // direct tile: rows i0+ly*4+r, cols j0+lx*4
#pragma unroll
    for (int r = 0; r < 4; ++r) {
        float4 v = make_float4(acc[r][0], acc[r][1], acc[r][2], acc[r][3]);
        *(float4*)&db[(size_t)(i0 + ly * 4 + r) * SS + j0 + lx * 4] = v;
    }
    if (it != jt) {
        // mirror straight from registers (d bitwise symmetric)
#pragma unroll
        for (int c = 0; c < 4; ++c) {
            float4 v = make_float4(acc[0][c], acc[1][c], acc[2][c], acc[3][c]);
            *(float4*)&db[(size_t)(j0 + lx * 4 + c) * SS + i0 + ly * 4] = v;
        }
    }
}

// ---------- wm finalize + topk (jax.lax.top_k) + initial assign, fused ----------
// wm > 0 strictly (means of uniform[0,1)), so float bits are order-monotonic.
__global__ __launch_bounds__(1024) void topk_assign_kernel(const float* __restrict__ part,
                                                           float* __restrict__ wm,
                                                           const float* __restrict__ d,
                                                           int* __restrict__ assign) {
    int b = blockIdx.x;
    int tid = threadIdx.x;          // == token index
    int lane = tid & 63, wv = tid >> 6;
    __shared__ ull red[16];
    __shared__ int ctr_s[KK];
    // finalize wm for this batch (same ascending-ic order as before)
    float v = 0.f;
#pragma unroll
    for (int ic = 0; ic < ICH; ++ic) v += part[((size_t)ic * BB + b) * SS + tid];
    v *= (1.0f / SS);
    wm[b * SS + tid] = v;
    // key: value-desc, tie -> smaller index (complemented idx, max-reduce)
    ull key = (((ull)__float_as_uint(v)) << 32) | (ull)(0xFFFFFFFFu - (unsigned)tid);
    for (int k = 0; k < KK; ++k) {
        ull kk = key;
#pragma unroll
        for (int off = 32; off; off >>= 1) {
            ull o = __shfl_down(kk, off, 64);
            if (o > kk) kk = o;
        }
        if (lane == 0) red[wv] = kk;
        __syncthreads();
        if (wv == 0) {
            ull k2 = (lane < 16) ? red[lane] : 0ull;
#pragma unroll
            for (int off = 8; off; off >>= 1) {
                ull o = __shfl_down(k2, off, 64);
                if (o > k2) k2 = o;
            }
            if (lane == 0) red[0] = k2;
        }
        __syncthreads();
        ull W = red[0];
        int widx = (int)(0xFFFFFFFFu - (unsigned)(W & 0xFFFFFFFFu));
        if (tid == widx) key = 0;            // remove winner
        if (tid == 0) ctr_s[k] = widx;
        __syncthreads();                      // protect red[] before next round
    }
    // initial assign: argmin_k d[ctr[k]][i] (d symmetric; coalesced over i)
    const float* db = d + (size_t)b * SS * SS;
    float bv = INFINITY;
    int bk = 0;
#pragma unroll
    for (int k = 0; k < KK; ++k) {
        float vv = db[(size_t)ctr_s[k] * SS + tid];
        if (vv < bv) { bv = vv; bk = k; }    // strict < keeps first k
    }
    assign[b * SS + tid] = bk;
}

// ---------- cost[b][i] = sum_{j: assign[j]==assign[i]} d[i][j]*wm[j] ----------
// 16 rows per block: wm+assign cached in LDS once (kills the 67 MB of
// redundant wm/assign re-fetch of the 1-row version), 4 waves x 4 rows,
// barrier-free per-row wave reduction.
#define RPB 16
__global__ __launch_bounds__(256) void cost_kernel(const float* __restrict__ d,
                                                   const float* __restrict__ wm,
                                                   const int* __restrict__ assign,
                                                   float* __restrict__ cost) {
    int b = blockIdx.y;
    int tid = threadIdx.x;
    int lane = tid & 63, wv = tid >> 6;
    __shared__ float wmv[SS];
    __shared__ int asg[SS];
    *(float4*)&wmv[tid * 4] = *(const float4*)&wm[b * SS + tid * 4];
    *(int4*)&asg[tid * 4] = *(const int4*)&assign[b * SS + tid * 4];
    __syncthreads();
    const float* db = d + (size_t)b * SS * SS;
#pragma unroll
    for (int r = 0; r < RPB / 4; ++r) {
        int i = blockIdx.x * RPB + wv * (RPB / 4) + r;
        int my = asg[i];
        const float* drow = db + (size_t)i * SS;
        float s = 0.f;
#pragma unroll
        for (int c = 0; c < SS / 256; ++c) {      // 4 sweeps of 64 lanes x float4
            int j = c * 256 + lane * 4;
            float4 dv = *(const float4*)&drow[j];
            float4 wv4 = *(const float4*)&wmv[j];
            int4 a4 = *(const int4*)&asg[j];
            s += (a4.x == my) ? dv.x * wv4.x : 0.f;
            s += (a4.y == my) ? dv.y * wv4.y : 0.f;
            s += (a4.z == my) ? dv.z * wv4.z : 0.f;
            s += (a4.w == my) ? dv.w * wv4.w : 0.f;
        }
#pragma unroll
        for (int off = 32; off; off >>= 1) s += __shfl_down(s, off, 64);
        if (lane == 0) cost[b * SS + i] = s;
    }
}

// ---------- medoid update (+ next assign, or final gather), widened ----------
// grid (4, B): each block redundantly computes all K medoids (cheap 8 KB
// LDS scan), then handles a 256-token quarter of the assign (or gather).
__global__ __launch_bounds__(1024) void update_assign_kernel(
        const float* __restrict__ d, const float* __restrict__ cost,
        int* __restrict__ assign, const float* __restrict__ x,
        float* __restrict__ out, int last) {
    int b = blockIdx.y;
    int q = blockIdx.x;             // quarter 0..3
    int tid = threadIdx.x;
    int lane = tid & 63, wv = tid >> 6;
    __shared__ float cost_s[SS];
    __shared__ int assign_s[SS];
    __shared__ int ctr_s[KK];
    __shared__ ull pk[4][256];
    cost_s[tid] = cost[b * SS + tid];
    assign_s[tid] = assign[b * SS + tid];
    __syncthreads();
    // per-cluster argmin: wave wv handles cluster k=wv.
    // cost >= 0 finite, so float bits are order-monotonic.
    ull best = ~0ull;
    int k = wv;   // 16 waves, 16 clusters
    for (int c = 0; c < SS / 64; ++c) {
        int i = c * 64 + lane;
        if (assign_s[i] == k) {
            ull key = (((ull)__float_as_uint(cost_s[i])) << 32) | (unsigned)i;
            if (key < best) best = key;
        }
    }
#pragma unroll
    for (int off = 32; off; off >>= 1) {
        ull o = __shfl_down(best, off, 64);
        if (o < best) best = o;
    }
    if (lane == 0) ctr_s[k] = (best == ~0ull) ? 0 : (int)(best & 0xFFFFFFFFu);
    __syncthreads();
    const float* db = d + (size_t)b * SS * SS;
    if (!last) {
        // next assign for this quarter's 256 tokens; 4 thread-groups each
        // cover 4 clusters; packed-key min => smallest dist, tie smallest k.
        int tok = q * 256 + (tid & 255);
        int g = tid >> 8;
        ull bk = ~0ull;
#pragma unroll
        for (int kk = 0; kk < 4; ++kk) {
            int k2 = g * 4 + kk;
            float vv = db[(size_t)ctr_s[k2] * SS + tok];
            ull key = (((ull)__float_as_uint(vv)) << 32) | (unsigned)k2;
            if (key < bk) bk = key;
        }
        pk[g][tid & 255] = bk;
        __syncthreads();
        if (tid < 256) {
            ull m = pk[0][tid];
            if (pk[1][tid] < m) m = pk[1][tid];
            if (pk[2][tid] < m) m = pk[2][tid];
            if (pk[3][tid] < m) m = pk[3][tid];
            assign[b * SS + q * 256 + tid] = (int)(m & 0xFFFFFFFFu);
        }
    } else {
        // final gather quarter: out[b][f][k] = x[b][f][ctr[k]]
        int e = q * 1024 + tid;     // FF*KK = 4096 elements total
        int f = e / KK, k2 = e % KK;
        out[((size_t)b * FF + f) * KK + k2] = x[((size_t)b * FF + f) * SS + ctr_s[k2]];
    }
}

extern "C" void kernel_launch(void* const* d_in, const int* in_sizes, int n_in,
                              void* d_out, int out_size, void* d_ws, size_t ws_size,
                              hipStream_t stream) {
    const float* x = (const float*)d_in[0];   // [B,F,S]
    const float* w = (const float*)d_in[1];   // [B,S,S]
    float* out = (float*)d_out;               // [B,F,K]

    char* ws = (char*)d_ws;
    float* d = (float*)ws;                              // B*S*S floats = 33.55 MB
    size_t off = (size_t)BB * SS * SS * sizeof(float);
    float* wm = (float*)(ws + off);   off += (size_t)BB * SS * sizeof(float);
    int* assign = (int*)(ws + off);   off += (size_t)BB * SS * sizeof(int);
    float* cost = (float*)(ws + off); off += (size_t)BB * SS * sizeof(float);
    float* part = (float*)(ws + off); // [ICH][B][S] = 256 KB (non-aliasing:
                                      // consumed by topk AFTER dist runs)

    wm_part_kernel<<<dim3(SS / 256, ICH, BB), 256, 0, stream>>>(w, part);
    // 528 triangular 32x32 wave-tiles per batch, 2 waves (2 tiles) per block
    dist_kernel<<<dim3(264, BB), 128, 0, stream>>>(x, d);
    topk_assign_kernel<<<BB, 1024, 0, stream>>>(part, wm, d, assign);
    for (int itr = 0; itr < ITERS; ++itr) {
        cost_kernel<<<dim3(SS / RPB, BB), 256, 0, stream>>>(d, wm, assign, cost);
        update_assign_kernel<<<dim3(4, BB), 1024, 0, stream>>>(d, cost, assign, x, out,
                                                               itr == ITERS - 1 ? 1 : 0);
    }
}